// Round 13
// baseline (182.060 us; speedup 1.0000x reference)
//
#include <hip/hip_runtime.h>

typedef unsigned short u16;
typedef __bf16 bf16x8 __attribute__((ext_vector_type(8)));
typedef float f32x4 __attribute__((ext_vector_type(4)));
typedef float f32x16 __attribute__((ext_vector_type(16)));
typedef unsigned u32x4 __attribute__((ext_vector_type(4)));

#define T_   2048
#define C_   2048
#define HD_  128
#define NH_  16
#define NKV_ 4
#define M_   4096   // B*T

typedef __attribute__((address_space(1))) const void* as1_cvp;
typedef __attribute__((address_space(3))) void* as3_vp;

__device__ __forceinline__ void gload16(const void* g, void* l) {
  __builtin_amdgcn_global_load_lds((as1_cvp)g, (as3_vp)l, 16, 0, 0);
}

__device__ __forceinline__ u16 f2bf(float f) {
  unsigned u = __builtin_bit_cast(unsigned, f);
  return (u16)((u + 0x7fffu + ((u >> 16) & 1u)) >> 16);
}

__device__ __forceinline__ float fexp2(float x) {
  float r;
  asm("v_exp_f32 %0, %1" : "=v"(r) : "v"(x));
  return r;
}

__device__ __forceinline__ unsigned cvtpk(float a, float b) {
  unsigned d;
  asm("v_cvt_pk_bf16_f32 %0, %1, %2" : "=v"(d) : "v"(a), "v"(b));
  return d;
}

// ---------------- fused prep: all fp32->bf16 conversions + RoPE folds + biases, ONE launch ----
__device__ __forceinline__ void cvt4(const float* __restrict__ src, u16* __restrict__ dst, int i) {
  float4 v = ((const float4*)src)[i];
  ushort4 r;
  r.x = f2bf(v.x); r.y = f2bf(v.y); r.z = f2bf(v.z); r.w = f2bf(v.w);
  ((ushort4*)dst)[i] = r;
}

__device__ __forceinline__ void rope_item(const float* __restrict__ W, u16* __restrict__ out, int i) {
  const int p  = i >> 9;
  const int c4 = (i & 511) << 2;
  const int h  = p >> 6;
  const int ii = p & 63;
  const float theta = __expf(-(float)ii * (9.210340371976184f / 64.0f));
  float s, c;
  __sincosf((float)h * theta, &s, &c);
  const size_t r0 = (size_t)(2 * p) * 2048 + c4;
  const size_t r1 = r0 + 2048;
  float4 a = *(const float4*)(W + r0);
  float4 b = *(const float4*)(W + r1);
  ushort4 o0, o1;
  o0.x = f2bf(a.x * c - b.x * s); o0.y = f2bf(a.y * c - b.y * s);
  o0.z = f2bf(a.z * c - b.z * s); o0.w = f2bf(a.w * c - b.w * s);
  o1.x = f2bf(b.x * c + a.x * s); o1.y = f2bf(b.y * c + a.y * s);
  o1.z = f2bf(b.z * c + a.z * s); o1.w = f2bf(b.w * c + a.w * s);
  *(ushort4*)(out + r0) = o0;
  *(ushort4*)(out + r1) = o1;
}

__global__ void prep_all(const float* __restrict__ x,    const float* __restrict__ wq_w,
                         const float* __restrict__ wk_w, const float* __restrict__ wv_w,
                         const float* __restrict__ cp_w, const float* __restrict__ wq_b,
                         const float* __restrict__ wk_b, const float* __restrict__ wv_b,
                         u16* __restrict__ xb,  u16* __restrict__ wqr, u16* __restrict__ wkr,
                         u16* __restrict__ wvb, u16* __restrict__ cpb, float* __restrict__ bqkv) {
  int i = blockIdx.x * blockDim.x + threadIdx.x;
  if (i < 2097152) { cvt4(x, xb, i); return; }
  i -= 2097152;
  if (i < 262144)  { cvt4(wv_w, wvb, i); return; }
  i -= 262144;
  if (i < 1048576) { cvt4(cp_w, cpb, i); return; }
  i -= 1048576;
  if (i < 524288)  { rope_item(wq_w, wqr, i); return; }
  i -= 524288;
  if (i < 131072)  { rope_item(wk_w, wkr, i); return; }
  i -= 131072;
  if (i < 1280) {
    const float* src = (i < 1024) ? wq_b : wk_b;
    float* dst = (i < 1024) ? bqkv : (bqkv + 2048);
    const int p = (i < 1024) ? i : (i - 1024);
    const int ii = p & 63;
    const float theta = __expf(-(float)ii * (9.210340371976184f / 64.0f));
    float s, c;
    __sincosf((float)(p >> 6) * theta, &s, &c);
    const float a = src[2 * p], b = src[2 * p + 1];
    dst[2 * p]     = a * c - b * s;
    dst[2 * p + 1] = b * c + a * s;
  } else if (i < 1536) {
    const int p = i - 1280;
    bqkv[2560 + 2 * p]     = wv_b[2 * p];
    bqkv[2560 + 2 * p + 1] = wv_b[2 * p + 1];
  }
}

// ---------------- 2-blocks/CU GEMM: C[M,N] = A[M,2048] @ W[N,2048]^T + bias ---------------
// BM=BN=128, BK=64, 256 threads = 4 waves (2M x 2N, wave tile 64x64). SAME proven gemm11
// pipeline (A 3-buf staged 2 ahead, B 2-buf staged 1 ahead, counted vmcnt(4), ONE barrier
// per K-step, unpinned body) but LDS = 3*16 + 2*16 = 80 KB -> TWO blocks per CU. The two
// co-resident blocks have independent barriers, so one block's LDS-read phase overlaps the
// other's MFMA phase (m114) — breaking the measured read/MFMA serialization of 1-block/CU.
// Swizzle: phys 16B-slot = logical ^ (row&7) via inverse-swizzled global source.
// MODE 0: fused QKV epilogue; MODE 1: fp32 [M,2048] out.
template<int MODE>
__global__ __launch_bounds__(256, 2)
void gemm17(const u16* __restrict__ A, const u16* __restrict__ W,
            const float* __restrict__ bias, void* __restrict__ op0,
            void* __restrict__ op1, void* __restrict__ op2, const float qscale) {
  constexpr int ABUF = 8192;               // u16 per A K-step buffer (128x64)
  constexpr int BBUF = 8192;               // u16 per B K-step buffer (128x64)
  __shared__ __align__(16) u16 sm[3 * ABUF + 2 * BBUF];   // 80 KB
  const int tid  = threadIdx.x;
  const int lane = tid & 63;
  const int wid  = tid >> 6;
  const int wr = wid >> 1, wc = wid & 1;   // 2M x 2N
  const int m0 = blockIdx.y << 7;
  const int n0 = blockIdx.x << 7;
  const int K  = C_;
  const int fr = lane & 15, g = lane >> 4;
  const int rs0 = ((g ^ (fr & 7)) << 3);
  const int rs1 = (((4 + g) ^ (fr & 7)) << 3);

  // staging: 4 slices each of A and B per K-step; linear LDS dest, pre-swizzled source
  size_t sof[4]; int sdst[4];
#pragma unroll
  for (int l = 0; l < 4; ++l) {
    const int j = l * 256 + tid, rl = j >> 3, sl = j & 7;
    sof[l]  = (size_t)rl * K + ((sl ^ (rl & 7)) << 3);
    sdst[l] = j * 8;
  }
  const u16* Ab = A + (size_t)m0 * K;
  const u16* Bb = W + (size_t)n0 * K;

  f32x4 acc[4][4] = {};

#define SA(l, ks, buf) gload16(Ab + (size_t)(ks) * 64 + sof[l], sm + (buf) * ABUF + sdst[l]);
#define SB(l, ks, buf) gload16(Bb + (size_t)(ks) * 64 + sof[l], sm + 3 * ABUF + (buf) * BBUF + sdst[l]);

  // prologue: B(0), A(0), A(1); vmcnt(4) leaves A(1) in flight
#pragma unroll
  for (int l = 0; l < 4; ++l) SB(l, 0, 0)
#pragma unroll
  for (int l = 0; l < 4; ++l) SA(l, 0, 0)
#pragma unroll
  for (int l = 0; l < 4; ++l) SA(l, 1, 1)
  asm volatile("s_waitcnt vmcnt(4)" ::: "memory");
  __builtin_amdgcn_s_barrier();
  __builtin_amdgcn_sched_barrier(0);

  int a0 = 0, a2 = 2;
  for (int s = 0; s < 32; ++s) {
    const int ab = a0 * ABUF;
    const int bb = 3 * ABUF + (s & 1) * BBUF;
    const int b1 = (s & 1) ^ 1;
    bf16x8 af0[4], af1[4], bq0[4], bq1[4];
#pragma unroll
    for (int ni = 0; ni < 4; ++ni)
      bq0[ni] = *(const bf16x8*)&sm[bb + (wc * 64 + ni * 16 + fr) * 64 + rs0];
#pragma unroll
    for (int mi = 0; mi < 4; ++mi)
      af0[mi] = *(const bf16x8*)&sm[ab + (wr * 64 + mi * 16 + fr) * 64 + rs0];
#pragma unroll
    for (int ni = 0; ni < 4; ++ni)
      bq1[ni] = *(const bf16x8*)&sm[bb + (wc * 64 + ni * 16 + fr) * 64 + rs1];
#pragma unroll
    for (int mi = 0; mi < 4; ++mi)
      af1[mi] = *(const bf16x8*)&sm[ab + (wr * 64 + mi * 16 + fr) * 64 + rs1];
    if (s < 31) {
#pragma unroll
      for (int l = 0; l < 4; ++l) SB(l, s + 1, b1)
    }
    if (s < 30) {
#pragma unroll
      for (int l = 0; l < 4; ++l) SA(l, s + 2, a2)
    }
    __builtin_amdgcn_s_setprio(1);
#pragma unroll
    for (int mi = 0; mi < 4; ++mi)
#pragma unroll
      for (int ni = 0; ni < 4; ++ni)
        acc[mi][ni] = __builtin_amdgcn_mfma_f32_16x16x32_bf16(af0[mi], bq0[ni], acc[mi][ni], 0, 0, 0);
#pragma unroll
    for (int mi = 0; mi < 4; ++mi)
#pragma unroll
      for (int ni = 0; ni < 4; ++ni)
        acc[mi][ni] = __builtin_amdgcn_mfma_f32_16x16x32_bf16(af1[mi], bq1[ni], acc[mi][ni], 0, 0, 0);
    __builtin_amdgcn_s_setprio(0);
    if (s < 30)       asm volatile("s_waitcnt vmcnt(4)" ::: "memory");
    else if (s == 30) asm volatile("s_waitcnt vmcnt(0)" ::: "memory");
    if (s < 31) {
      __builtin_amdgcn_s_barrier();
      __builtin_amdgcn_sched_barrier(0);
    }
    a0 = (a0 == 2) ? 0 : a0 + 1;
    a2 = (a2 == 2) ? 0 : a2 + 1;
  }
#undef SA
#undef SB

#pragma unroll
  for (int mi = 0; mi < 4; ++mi) {
    const int rg0 = m0 + wr * 64 + mi * 16 + ((lane >> 4) << 2);
#pragma unroll
    for (int ni = 0; ni < 4; ++ni) {
      const int cg = n0 + wc * 64 + ni * 16 + fr;
      const float bb2 = bias[cg];
#pragma unroll
      for (int r = 0; r < 4; ++r) {
        float v = acc[mi][ni][r] + bb2;
        const int rg = rg0 + r;
        if (MODE == 1) {
          ((float*)op0)[(size_t)rg * C_ + cg] = v;
        } else {
          const int b = rg >> 11, t = rg & (T_ - 1);
          if (cg < 2048) {
            const int h = cg >> 7, d = cg & 127;
            ((u16*)op0)[((((size_t)b * NH_ + h) * T_ + t) << 7) + d] = f2bf(v * qscale);
          } else if (cg < 2560) {
            const int c2 = cg - 2048, h = c2 >> 7, d = c2 & 127;
            ((u16*)op1)[((((size_t)b * NKV_ + h) * T_ + t) << 7) + d] = f2bf(v);
          } else {
            const int c2 = cg - 2560, h = c2 >> 7, d = c2 & 127;
            ((u16*)op2)[(((size_t)b * NKV_ + h) * HD_ + d) * T_ + t] = f2bf(v);
          }
        }
      }
    }
  }
}

// ---------------- causal GQA flash attention (round-9 known-good) ------------
__device__ __forceinline__ void stage_kv(u16* dst, const u16* __restrict__ kg,
                                         const u16* __restrict__ vg, int lane, int w) {
#pragma unroll
  for (int r = 0; r < 4; ++r) {
    const int row = r * 16 + w * 4 + (lane >> 4);
    const int cg  = (lane & 15) ^ (row & 7);
    gload16(kg + (size_t)row * 128 + cg * 8, dst + row * 128 + (lane & 15) * 8);
  }
#pragma unroll
  for (int r = 0; r < 4; ++r) {
    const int row = r * 32 + w * 8 + (lane >> 3);
    const int cg  = (lane & 7) ^ (row & 7);
    gload16(vg + (size_t)row * T_ + cg * 8, dst + 8192 + row * 64 + (lane & 7) * 8);
  }
}

__global__ __launch_bounds__(256, 2)
void attn2(const u16* __restrict__ q, const u16* __restrict__ k,
           const u16* __restrict__ vt, u16* __restrict__ y) {
  __shared__ __align__(16) u16 sm[32768];
  const int tid  = threadIdx.x;
  const int lane = tid & 63;
  const int w    = tid >> 6;
  const int hi   = lane >> 5;
  const int l5   = lane & 31;
  const int h = blockIdx.y;
  const int b = blockIdx.z;
  const int qt = b ? (int)blockIdx.x : (15 - (int)blockIdx.x);
  const int q0  = qt << 7;
  const int q0w = q0 + w * 32;
  const int nkv = 2 * qt + 2;
  const size_t qbase = (((size_t)b * NH_ + h) * T_ + q0) * HD_;
  const size_t kbase = ((size_t)b * NKV_ + (h >> 2)) * (size_t)T_ * HD_;
  const size_t vbase = ((size_t)b * NKV_ + (h >> 2)) * (size_t)HD_ * T_;

#pragma unroll
  for (int r = 0; r < 8; ++r) {
    const int row = r * 16 + w * 4 + (lane >> 4);
    const int cg  = (lane & 15) ^ (row & 7);
    gload16(q + qbase + (size_t)row * 128 + cg * 8, sm + row * 128 + (lane & 15) * 8);
  }
  __syncthreads();
  bf16x8 qf[8];
  {
    const int row = w * 32 + l5;
#pragma unroll
    for (int kd = 0; kd < 8; ++kd)
      qf[kd] = *(const bf16x8*)&sm[row * 128 + ((((kd << 1) | hi) ^ (row & 7)) << 3)];
  }
  __syncthreads();
  stage_kv(sm, k + kbase, vt + vbase, lane, w);

  f32x16 o[4] = {};
  float m = -1e30f, l = 0.f;

  for (int kv = 0; kv < nkv; ++kv) {
    __syncthreads();
    const int buf = kv & 1;
    if (kv + 1 < nkv)
      stage_kv(sm + ((buf ^ 1) << 14),
               k + kbase + ((size_t)(kv + 1) << 6) * 128,
               vt + vbase + ((kv + 1) << 6), lane, w);

    if ((kv << 6) <= q0w + 31) {
      const u16* Ks = sm + (buf << 14);
      const u16* Vs = Ks + 8192;

      f32x16 st[2] = {};
      __builtin_amdgcn_s_setprio(1);
#pragma unroll
      for (int kt = 0; kt < 2; ++kt) {
        const int krow = kt * 32 + l5;
#pragma unroll
        for (int kd = 0; kd < 8; ++kd) {
          bf16x8 ka = *(const bf16x8*)&Ks[krow * 128 + ((((kd << 1) | hi) ^ (l5 & 7)) << 3)];
          st[kt] = __builtin_amdgcn_mfma_f32_32x32x16_bf16(ka, qf[kd], st[kt], 0, 0, 0);
        }
      }
      __builtin_amdgcn_s_setprio(0);

      if ((kv << 6) + 63 > q0w) {
        const int qg = q0w + l5;
#pragma unroll
        for (int kt = 0; kt < 2; ++kt)
#pragma unroll
          for (int r = 0; r < 16; ++r) {
            const int kg = (kv << 6) + kt * 32 + (r & 3) + ((r >> 2) << 3) + (hi << 2);
            if (kg > qg) st[kt][r] = -3.0e38f;
          }
      }

      float pmax = -3.0e38f;
#pragma unroll
      for (int kt = 0; kt < 2; ++kt)
#pragma unroll
        for (int r = 0; r < 16; ++r) pmax = fmaxf(pmax, st[kt][r]);
      pmax = fmaxf(pmax, __shfl_xor(pmax, 32));
      if (!__all(pmax - m <= 8.0f)) {
        const float mn = fmaxf(m, pmax);
        const float f = fexp2(m - mn);
        m = mn;
        l *= f;
#pragma unroll
        for (int r = 0; r < 16; ++r) {
          const float fr = __shfl(f, (r & 3) + ((r >> 2) << 3) + (hi << 2));
          o[0][r] *= fr; o[1][r] *= fr; o[2][r] *= fr; o[3][r] *= fr;
        }
      }

      float rs = 0.f;
#pragma unroll
      for (int kt = 0; kt < 2; ++kt) {
#pragma unroll
        for (int s = 0; s < 2; ++s) {
          float e0 = fexp2(st[kt][8 * s + 0] - m), e1 = fexp2(st[kt][8 * s + 1] - m);
          float e2 = fexp2(st[kt][8 * s + 2] - m), e3 = fexp2(st[kt][8 * s + 3] - m);
          float e4 = fexp2(st[kt][8 * s + 4] - m), e5 = fexp2(st[kt][8 * s + 5] - m);
          float e6 = fexp2(st[kt][8 * s + 6] - m), e7 = fexp2(st[kt][8 * s + 7] - m);
          rs += ((e0 + e1) + (e2 + e3)) + ((e4 + e5) + (e6 + e7));
          const unsigned wL0 = cvtpk(e0, e1), wL1 = cvtpk(e2, e3);
          const unsigned wH0 = cvtpk(e4, e5), wH1 = cvtpk(e6, e7);
          const unsigned s0 = hi ? wL0 : wH0, s1 = hi ? wL1 : wH1;
          const unsigned r0 = __shfl_xor(s0, 32), r1 = __shfl_xor(s1, 32);
          u32x4 fw;
          fw.x = hi ? r0 : wL0; fw.y = hi ? r1 : wL1;
          fw.z = hi ? wH0 : r0; fw.w = hi ? wH1 : r1;
          const bf16x8 pa = __builtin_bit_cast(bf16x8, fw);
          const int ch = (((kt * 2 + s) << 1) | hi) ^ (l5 & 7);
          __builtin_amdgcn_s_setprio(1);
#pragma unroll
          for (int ds = 0; ds < 4; ++ds) {
            const int vrow = ds * 32 + l5;
            bf16x8 vb = *(const bf16x8*)&Vs[vrow * 64 + (ch << 3)];
            o[ds] = __builtin_amdgcn_mfma_f32_32x32x16_bf16(pa, vb, o[ds], 0, 0, 0);
          }
          __builtin_amdgcn_s_setprio(0);
        }
      }
      rs += __shfl_xor(rs, 32);
      l += rs;
    }
  }

  const float linv = 1.0f / l;
#pragma unroll
  for (int r = 0; r < 16; ++r) {
    const int crow = (r & 3) + ((r >> 2) << 3) + (hi << 2);
    const float lf = __shfl(linv, crow);
    const int qg = q0w + crow;
    const size_t rowoff = (((size_t)(b << 11) + qg) << 11) + (h << 7) + l5;
#pragma unroll
    for (int ds = 0; ds < 4; ++ds)
      y[rowoff + ds * 32] = f2bf(o[ds][r] * lf);
  }
}

// ---------------- launch ----------------
extern "C" void kernel_launch(void* const* d_in, const int* in_sizes, int n_in,
                              void* d_out, int out_size, void* d_ws, size_t ws_size,
                              hipStream_t stream) {
  (void)in_sizes; (void)n_in; (void)out_size; (void)ws_size;
  const float* x    = (const float*)d_in[0];
  const float* wq_w = (const float*)d_in[1];
  const float* wq_b = (const float*)d_in[2];
  const float* wk_w = (const float*)d_in[3];
  const float* wk_b = (const float*)d_in[4];
  const float* wv_w = (const float*)d_in[5];
  const float* wv_b = (const float*)d_in[6];
  const float* cp_w = (const float*)d_in[7];
  const float* cp_b = (const float*)d_in[8];

  char* ws = (char*)d_ws;
  u16* xb  = (u16*)ws;  ws += (size_t)M_ * C_ * 2;
  u16* wqr = (u16*)ws;  ws += (size_t)C_ * C_ * 2;
  u16* wkr = (u16*)ws;  ws += (size_t)512 * C_ * 2;
  u16* wvb = (u16*)ws;  ws += (size_t)512 * C_ * 2;
  u16* cpb = (u16*)ws;  ws += (size_t)C_ * C_ * 2;
  u16* qb  = (u16*)ws;  ws += (size_t)M_ * C_ * 2;
  u16* kb  = (u16*)ws;  ws += (size_t)M_ * 512 * 2;
  u16* vtb = (u16*)ws;  ws += (size_t)M_ * 512 * 2;
  float* bqkv = (float*)ws; ws += 3072 * 4;
  u16* yb = xb;

  prep_all<<<15878, 256, 0, stream>>>(x, wq_w, wk_w, wv_w, cp_w, wq_b, wk_b, wv_b,
                                      xb, wqr, wkr, wvb, cpb, bqkv);

  const float qscale = 0.08838834764831843f * 1.4426950408889634f;
  gemm17<0><<<dim3(24, 32), 256, 0, stream>>>(xb, wqr, bqkv, qb, kb, vtb, qscale);

  attn2<<<dim3(16, 16, 2), 256, 0, stream>>>(qb, kb, vtb, yb);

  gemm17<1><<<dim3(16, 32), 256, 0, stream>>>(yb, cpb, cp_b, (float*)d_out,
                                              nullptr, nullptr, 1.0f);
}

// Round 14
// 174.323 us; speedup vs baseline: 1.0444x; 1.0444x over previous
//
#include <hip/hip_runtime.h>

typedef unsigned short u16;
typedef __bf16 bf16x8 __attribute__((ext_vector_type(8)));
typedef float f32x4 __attribute__((ext_vector_type(4)));
typedef float f32x16 __attribute__((ext_vector_type(16)));
typedef unsigned u32x4 __attribute__((ext_vector_type(4)));

#define T_   2048
#define C_   2048
#define HD_  128
#define NH_  16
#define NKV_ 4
#define M_   4096   // B*T

typedef __attribute__((address_space(1))) const void* as1_cvp;
typedef __attribute__((address_space(3))) void* as3_vp;

__device__ __forceinline__ void gload16(const void* g, void* l) {
  __builtin_amdgcn_global_load_lds((as1_cvp)g, (as3_vp)l, 16, 0, 0);
}

__device__ __forceinline__ u16 f2bf(float f) {
  unsigned u = __builtin_bit_cast(unsigned, f);
  return (u16)((u + 0x7fffu + ((u >> 16) & 1u)) >> 16);
}

__device__ __forceinline__ float fexp2(float x) {
  float r;
  asm("v_exp_f32 %0, %1" : "=v"(r) : "v"(x));
  return r;
}

__device__ __forceinline__ unsigned cvtpk(float a, float b) {
  unsigned d;
  asm("v_cvt_pk_bf16_f32 %0, %1, %2" : "=v"(d) : "v"(a), "v"(b));
  return d;
}

// ---------------- fused prep: all fp32->bf16 conversions + RoPE folds + biases, ONE launch ----
__device__ __forceinline__ void cvt4(const float* __restrict__ src, u16* __restrict__ dst, int i) {
  float4 v = ((const float4*)src)[i];
  ushort4 r;
  r.x = f2bf(v.x); r.y = f2bf(v.y); r.z = f2bf(v.z); r.w = f2bf(v.w);
  ((ushort4*)dst)[i] = r;
}

// RoPE fold on weight-row pairs (angle indexed by HEAD, per reference quirk)
__device__ __forceinline__ void rope_item(const float* __restrict__ W, u16* __restrict__ out, int i) {
  const int p  = i >> 9;            // row-pair index
  const int c4 = (i & 511) << 2;    // float column
  const int h  = p >> 6;
  const int ii = p & 63;
  const float theta = __expf(-(float)ii * (9.210340371976184f / 64.0f));
  float s, c;
  __sincosf((float)h * theta, &s, &c);
  const size_t r0 = (size_t)(2 * p) * 2048 + c4;
  const size_t r1 = r0 + 2048;
  float4 a = *(const float4*)(W + r0);
  float4 b = *(const float4*)(W + r1);
  ushort4 o0, o1;
  o0.x = f2bf(a.x * c - b.x * s); o0.y = f2bf(a.y * c - b.y * s);
  o0.z = f2bf(a.z * c - b.z * s); o0.w = f2bf(a.w * c - b.w * s);
  o1.x = f2bf(b.x * c + a.x * s); o1.y = f2bf(b.y * c + a.y * s);
  o1.z = f2bf(b.z * c + a.z * s); o1.w = f2bf(b.w * c + a.w * s);
  *(ushort4*)(out + r0) = o0;
  *(ushort4*)(out + r1) = o1;
}

__global__ void prep_all(const float* __restrict__ x,    const float* __restrict__ wq_w,
                         const float* __restrict__ wk_w, const float* __restrict__ wv_w,
                         const float* __restrict__ cp_w, const float* __restrict__ wq_b,
                         const float* __restrict__ wk_b, const float* __restrict__ wv_b,
                         u16* __restrict__ xb,  u16* __restrict__ wqr, u16* __restrict__ wkr,
                         u16* __restrict__ wvb, u16* __restrict__ cpb, float* __restrict__ bqkv) {
  int i = blockIdx.x * blockDim.x + threadIdx.x;
  if (i < 2097152) { cvt4(x, xb, i); return; }            // x  [4096x2048]
  i -= 2097152;
  if (i < 262144)  { cvt4(wv_w, wvb, i); return; }        // wv [512x2048]
  i -= 262144;
  if (i < 1048576) { cvt4(cp_w, cpb, i); return; }        // cp [2048x2048]
  i -= 1048576;
  if (i < 524288)  { rope_item(wq_w, wqr, i); return; }   // wq rope (1024 pairs x 512)
  i -= 524288;
  if (i < 131072)  { rope_item(wk_w, wkr, i); return; }   // wk rope (256 pairs x 512)
  i -= 131072;
  if (i < 1280) {                                          // rope'd biases
    const float* src = (i < 1024) ? wq_b : wk_b;
    float* dst = (i < 1024) ? bqkv : (bqkv + 2048);
    const int p = (i < 1024) ? i : (i - 1024);
    const int ii = p & 63;
    const float theta = __expf(-(float)ii * (9.210340371976184f / 64.0f));
    float s, c;
    __sincosf((float)(p >> 6) * theta, &s, &c);
    const float a = src[2 * p], b = src[2 * p + 1];
    dst[2 * p]     = a * c - b * s;
    dst[2 * p + 1] = b * c + a * s;
  } else if (i < 1536) {
    const int p = i - 1280;
    bqkv[2560 + 2 * p]     = wv_b[2 * p];
    bqkv[2560 + 2 * p + 1] = wv_b[2 * p + 1];
  }
}

// ---------------- compiler-interleaved GEMM (best-known): C = A @ W^T + bias --------------
// BM=256, K-step 64, 8 waves as 4M x 2N (wave tile 64 x BN/2). A TRIPLE-buffered (staged
// 2 K-steps ahead), B double-buffered (1 ahead); issue order B(s+1) then A(s+2) makes the
// once-per-K-step s_waitcnt vmcnt(4) retire exactly {A(s+1),B(s+1)} while A(s+2) stays in
// flight. ONE s_barrier per K-step; body UNPINNED so the compiler interleaves MFMA with
// counted lgkmcnt and drifting waves overlap the LDS and MFMA pipes.
// Swizzle: phys 16B-slot = logical ^ (row&7) via inverse-swizzled global source (rule 21;
// measured 0 bank conflicts). MODE 0: fused QKV epilogue (BN=192); MODE 1: fp32 out (BN=128).
template<int BN, int MODE>
__global__ __launch_bounds__(512)
void gemm11(const u16* __restrict__ A, const u16* __restrict__ W,
            const float* __restrict__ bias, void* __restrict__ op0,
            void* __restrict__ op1, void* __restrict__ op2, const float qscale) {
  constexpr int NREP = BN / 32;
  constexpr int ABUF = 16384;
  constexpr int BBUF = BN * 64;
  constexpr int NBL  = BN / 64;
  __shared__ __align__(16) u16 sm[3 * ABUF + 2 * BBUF];
  const int tid  = threadIdx.x;
  const int lane = tid & 63;
  const int wid  = tid >> 6;
  const int wr = wid >> 1, wc = wid & 1;
  const int m0 = blockIdx.y << 8;
  const int n0 = blockIdx.x * BN;
  const int K  = C_;
  const int fr = lane & 15, g = lane >> 4;
  const int rs0 = ((g ^ (fr & 7)) << 3);
  const int rs1 = (((4 + g) ^ (fr & 7)) << 3);

  size_t sofA[4]; int sdstA[4];
#pragma unroll
  for (int l = 0; l < 4; ++l) {
    const int j = l * 512 + tid, rl = j >> 3, sl = j & 7;
    sofA[l] = (size_t)rl * K + ((sl ^ (rl & 7)) << 3);
    sdstA[l] = j * 8;
  }
  size_t sofB[NBL]; int sdstB[NBL];
#pragma unroll
  for (int l = 0; l < NBL; ++l) {
    const int j = l * 512 + tid, rl = j >> 3, sl = j & 7;
    sofB[l] = (size_t)rl * K + ((sl ^ (rl & 7)) << 3);
    sdstB[l] = j * 8;
  }
  const u16* Ab = A + (size_t)m0 * K;
  const u16* Bb = W + (size_t)n0 * K;

  f32x4 acc[4][NREP] = {};

#define SA(l, ks, buf) gload16(Ab + (size_t)(ks) * 64 + sofA[l], sm + (buf) * ABUF + sdstA[l]);
#define SB(l, ks, buf) gload16(Bb + (size_t)(ks) * 64 + sofB[l], sm + 3 * ABUF + (buf) * BBUF + sdstB[l]);

  // prologue: B(0), A(0), A(1); vmcnt(4) leaves A(1) in flight
#pragma unroll
  for (int l = 0; l < NBL; ++l) SB(l, 0, 0)
#pragma unroll
  for (int l = 0; l < 4; ++l) SA(l, 0, 0)
#pragma unroll
  for (int l = 0; l < 4; ++l) SA(l, 1, 1)
  asm volatile("s_waitcnt vmcnt(4)" ::: "memory");
  __builtin_amdgcn_s_barrier();
  __builtin_amdgcn_sched_barrier(0);

  int a0 = 0, a2 = 2;
  for (int s = 0; s < 32; ++s) {
    const int ab = a0 * ABUF;
    const int bb = 3 * ABUF + (s & 1) * BBUF;
    const int b1 = (s & 1) ^ 1;
    bf16x8 af0[4], af1[4], bq0[NREP], bq1[NREP];
#pragma unroll
    for (int ni = 0; ni < NREP; ++ni)
      bq0[ni] = *(const bf16x8*)&sm[bb + (wc * (BN / 2) + ni * 16 + fr) * 64 + rs0];
#pragma unroll
    for (int mi = 0; mi < 4; ++mi)
      af0[mi] = *(const bf16x8*)&sm[ab + (wr * 64 + mi * 16 + fr) * 64 + rs0];
#pragma unroll
    for (int ni = 0; ni < NREP; ++ni)
      bq1[ni] = *(const bf16x8*)&sm[bb + (wc * (BN / 2) + ni * 16 + fr) * 64 + rs1];
#pragma unroll
    for (int mi = 0; mi < 4; ++mi)
      af1[mi] = *(const bf16x8*)&sm[ab + (wr * 64 + mi * 16 + fr) * 64 + rs1];
    if (s < 31) {
#pragma unroll
      for (int l = 0; l < NBL; ++l) SB(l, s + 1, b1)
    }
    if (s < 30) {
#pragma unroll
      for (int l = 0; l < 4; ++l) SA(l, s + 2, a2)
    }
    __builtin_amdgcn_s_setprio(1);
#pragma unroll
    for (int mi = 0; mi < 4; ++mi)
#pragma unroll
      for (int ni = 0; ni < NREP; ++ni)
        acc[mi][ni] = __builtin_amdgcn_mfma_f32_16x16x32_bf16(af0[mi], bq0[ni], acc[mi][ni], 0, 0, 0);
#pragma unroll
    for (int mi = 0; mi < 4; ++mi)
#pragma unroll
      for (int ni = 0; ni < NREP; ++ni)
        acc[mi][ni] = __builtin_amdgcn_mfma_f32_16x16x32_bf16(af1[mi], bq1[ni], acc[mi][ni], 0, 0, 0);
    __builtin_amdgcn_s_setprio(0);
    if (s < 30)       asm volatile("s_waitcnt vmcnt(4)" ::: "memory");
    else if (s == 30) asm volatile("s_waitcnt vmcnt(0)" ::: "memory");
    if (s < 31) {
      __builtin_amdgcn_s_barrier();
      __builtin_amdgcn_sched_barrier(0);
    }
    a0 = (a0 == 2) ? 0 : a0 + 1;
    a2 = (a2 == 2) ? 0 : a2 + 1;
  }
#undef SA
#undef SB

#pragma unroll
  for (int mi = 0; mi < 4; ++mi) {
    const int rg0 = m0 + wr * 64 + mi * 16 + ((lane >> 4) << 2);
#pragma unroll
    for (int ni = 0; ni < NREP; ++ni) {
      const int cg = n0 + wc * (BN / 2) + ni * 16 + fr;
      const float bb2 = bias[cg];
#pragma unroll
      for (int r = 0; r < 4; ++r) {
        float v = acc[mi][ni][r] + bb2;
        const int rg = rg0 + r;
        if (MODE == 1) {
          ((float*)op0)[(size_t)rg * C_ + cg] = v;
        } else {
          const int b = rg >> 11, t = rg & (T_ - 1);
          if (cg < 2048) {
            const int h = cg >> 7, d = cg & 127;
            ((u16*)op0)[((((size_t)b * NH_ + h) * T_ + t) << 7) + d] = f2bf(v * qscale);
          } else if (cg < 2560) {
            const int c2 = cg - 2048, h = c2 >> 7, d = c2 & 127;
            ((u16*)op1)[((((size_t)b * NKV_ + h) * T_ + t) << 7) + d] = f2bf(v);
          } else {
            const int c2 = cg - 2560, h = c2 >> 7, d = c2 & 127;
            ((u16*)op2)[(((size_t)b * NKV_ + h) * HD_ + d) * T_ + t] = f2bf(v);
          }
        }
      }
    }
  }
}

// ---------------- causal GQA flash attention (best-known) ------------
__device__ __forceinline__ void stage_kv(u16* dst, const u16* __restrict__ kg,
                                         const u16* __restrict__ vg, int lane, int w) {
#pragma unroll
  for (int r = 0; r < 4; ++r) {
    const int row = r * 16 + w * 4 + (lane >> 4);
    const int cg  = (lane & 15) ^ (row & 7);
    gload16(kg + (size_t)row * 128 + cg * 8, dst + row * 128 + (lane & 15) * 8);
  }
#pragma unroll
  for (int r = 0; r < 4; ++r) {
    const int row = r * 32 + w * 8 + (lane >> 3);
    const int cg  = (lane & 7) ^ (row & 7);
    gload16(vg + (size_t)row * T_ + cg * 8, dst + 8192 + row * 64 + (lane & 7) * 8);
  }
}

__global__ __launch_bounds__(256, 2)
void attn2(const u16* __restrict__ q, const u16* __restrict__ k,
           const u16* __restrict__ vt, u16* __restrict__ y) {
  __shared__ __align__(16) u16 sm[32768];
  const int tid  = threadIdx.x;
  const int lane = tid & 63;
  const int w    = tid >> 6;
  const int hi   = lane >> 5;
  const int l5   = lane & 31;
  const int h = blockIdx.y;
  const int b = blockIdx.z;
  // complementary pairing: co-resident (x,y,0)/(x,y,1) get qt summing to 15 -> uniform CU load
  const int qt = b ? (int)blockIdx.x : (15 - (int)blockIdx.x);
  const int q0  = qt << 7;
  const int q0w = q0 + w * 32;
  const int nkv = 2 * qt + 2;
  const size_t qbase = (((size_t)b * NH_ + h) * T_ + q0) * HD_;
  const size_t kbase = ((size_t)b * NKV_ + (h >> 2)) * (size_t)T_ * HD_;
  const size_t vbase = ((size_t)b * NKV_ + (h >> 2)) * (size_t)HD_ * T_;

#pragma unroll
  for (int r = 0; r < 8; ++r) {
    const int row = r * 16 + w * 4 + (lane >> 4);
    const int cg  = (lane & 15) ^ (row & 7);
    gload16(q + qbase + (size_t)row * 128 + cg * 8, sm + row * 128 + (lane & 15) * 8);
  }
  __syncthreads();
  bf16x8 qf[8];
  {
    const int row = w * 32 + l5;
#pragma unroll
    for (int kd = 0; kd < 8; ++kd)
      qf[kd] = *(const bf16x8*)&sm[row * 128 + ((((kd << 1) | hi) ^ (row & 7)) << 3)];
  }
  __syncthreads();
  stage_kv(sm, k + kbase, vt + vbase, lane, w);

  f32x16 o[4] = {};
  float m = -1e30f, l = 0.f;

  for (int kv = 0; kv < nkv; ++kv) {
    __syncthreads();
    const int buf = kv & 1;
    if (kv + 1 < nkv)
      stage_kv(sm + ((buf ^ 1) << 14),
               k + kbase + ((size_t)(kv + 1) << 6) * 128,
               vt + vbase + ((kv + 1) << 6), lane, w);

    if ((kv << 6) <= q0w + 31) {
      const u16* Ks = sm + (buf << 14);
      const u16* Vs = Ks + 8192;

      f32x16 st[2] = {};
      __builtin_amdgcn_s_setprio(1);
#pragma unroll
      for (int kt = 0; kt < 2; ++kt) {
        const int krow = kt * 32 + l5;
#pragma unroll
        for (int kd = 0; kd < 8; ++kd) {
          bf16x8 ka = *(const bf16x8*)&Ks[krow * 128 + ((((kd << 1) | hi) ^ (l5 & 7)) << 3)];
          st[kt] = __builtin_amdgcn_mfma_f32_32x32x16_bf16(ka, qf[kd], st[kt], 0, 0, 0);
        }
      }
      __builtin_amdgcn_s_setprio(0);

      if ((kv << 6) + 63 > q0w) {
        const int qg = q0w + l5;
#pragma unroll
        for (int kt = 0; kt < 2; ++kt)
#pragma unroll
          for (int r = 0; r < 16; ++r) {
            const int kg = (kv << 6) + kt * 32 + (r & 3) + ((r >> 2) << 3) + (hi << 2);
            if (kg > qg) st[kt][r] = -3.0e38f;
          }
      }

      float pmax = -3.0e38f;
#pragma unroll
      for (int kt = 0; kt < 2; ++kt)
#pragma unroll
        for (int r = 0; r < 16; ++r) pmax = fmaxf(pmax, st[kt][r]);
      pmax = fmaxf(pmax, __shfl_xor(pmax, 32));
      if (!__all(pmax - m <= 8.0f)) {
        const float mn = fmaxf(m, pmax);
        const float f = fexp2(m - mn);
        m = mn;
        l *= f;
#pragma unroll
        for (int r = 0; r < 16; ++r) {
          const float fr = __shfl(f, (r & 3) + ((r >> 2) << 3) + (hi << 2));
          o[0][r] *= fr; o[1][r] *= fr; o[2][r] *= fr; o[3][r] *= fr;
        }
      }

      float rs = 0.f;
#pragma unroll
      for (int kt = 0; kt < 2; ++kt) {
#pragma unroll
        for (int s = 0; s < 2; ++s) {
          float e0 = fexp2(st[kt][8 * s + 0] - m), e1 = fexp2(st[kt][8 * s + 1] - m);
          float e2 = fexp2(st[kt][8 * s + 2] - m), e3 = fexp2(st[kt][8 * s + 3] - m);
          float e4 = fexp2(st[kt][8 * s + 4] - m), e5 = fexp2(st[kt][8 * s + 5] - m);
          float e6 = fexp2(st[kt][8 * s + 6] - m), e7 = fexp2(st[kt][8 * s + 7] - m);
          rs += ((e0 + e1) + (e2 + e3)) + ((e4 + e5) + (e6 + e7));
          const unsigned wL0 = cvtpk(e0, e1), wL1 = cvtpk(e2, e3);
          const unsigned wH0 = cvtpk(e4, e5), wH1 = cvtpk(e6, e7);
          const unsigned s0 = hi ? wL0 : wH0, s1 = hi ? wL1 : wH1;
          const unsigned r0 = __shfl_xor(s0, 32), r1 = __shfl_xor(s1, 32);
          u32x4 fw;
          fw.x = hi ? r0 : wL0; fw.y = hi ? r1 : wL1;
          fw.z = hi ? wH0 : r0; fw.w = hi ? wH1 : r1;
          const bf16x8 pa = __builtin_bit_cast(bf16x8, fw);
          const int ch = (((kt * 2 + s) << 1) | hi) ^ (l5 & 7);
          __builtin_amdgcn_s_setprio(1);
#pragma unroll
          for (int ds = 0; ds < 4; ++ds) {
            const int vrow = ds * 32 + l5;
            bf16x8 vb = *(const bf16x8*)&Vs[vrow * 64 + (ch << 3)];
            o[ds] = __builtin_amdgcn_mfma_f32_32x32x16_bf16(pa, vb, o[ds], 0, 0, 0);
          }
          __builtin_amdgcn_s_setprio(0);
        }
      }
      rs += __shfl_xor(rs, 32);
      l += rs;
    }
  }

  const float linv = 1.0f / l;
#pragma unroll
  for (int r = 0; r < 16; ++r) {
    const int crow = (r & 3) + ((r >> 2) << 3) + (hi << 2);
    const float lf = __shfl(linv, crow);
    const int qg = q0w + crow;
    const size_t rowoff = (((size_t)(b << 11) + qg) << 11) + (h << 7) + l5;
#pragma unroll
    for (int ds = 0; ds < 4; ++ds)
      y[rowoff + ds * 32] = f2bf(o[ds][r] * lf);
  }
}

// ---------------- launch ----------------
extern "C" void kernel_launch(void* const* d_in, const int* in_sizes, int n_in,
                              void* d_out, int out_size, void* d_ws, size_t ws_size,
                              hipStream_t stream) {
  (void)in_sizes; (void)n_in; (void)out_size; (void)ws_size;
  const float* x    = (const float*)d_in[0];
  const float* wq_w = (const float*)d_in[1];
  const float* wq_b = (const float*)d_in[2];
  const float* wk_w = (const float*)d_in[3];
  const float* wk_b = (const float*)d_in[4];
  const float* wv_w = (const float*)d_in[5];
  const float* wv_b = (const float*)d_in[6];
  const float* cp_w = (const float*)d_in[7];
  const float* cp_b = (const float*)d_in[8];

  char* ws = (char*)d_ws;
  u16* xb  = (u16*)ws;  ws += (size_t)M_ * C_ * 2;        // x bf16; later reused as y
  u16* wqr = (u16*)ws;  ws += (size_t)C_ * C_ * 2;        // rotated wq
  u16* wkr = (u16*)ws;  ws += (size_t)512 * C_ * 2;       // rotated wk
  u16* wvb = (u16*)ws;  ws += (size_t)512 * C_ * 2;       // wv bf16
  u16* cpb = (u16*)ws;  ws += (size_t)C_ * C_ * 2;
  u16* qb  = (u16*)ws;  ws += (size_t)M_ * C_ * 2;
  u16* kb  = (u16*)ws;  ws += (size_t)M_ * 512 * 2;
  u16* vtb = (u16*)ws;  ws += (size_t)M_ * 512 * 2;
  float* bqkv = (float*)ws; ws += 3072 * 4;               // concat bias (fp32)
  u16* yb = xb;

  // single fused prep launch: 4,064,768 items = 15878 blocks x 256
  prep_all<<<15878, 256, 0, stream>>>(x, wq_w, wk_w, wv_w, cp_w, wq_b, wk_b, wv_b,
                                      xb, wqr, wkr, wvb, cpb, bqkv);

  // Q pre-scaled by log2e / sqrt(HD) so attention softmax runs in exp2 domain
  const float qscale = 0.08838834764831843f * 1.4426950408889634f;
  gemm11<192, 0><<<dim3(16, 16), 512, 0, stream>>>(xb, wqr, bqkv, qb, kb, vtb, qscale);

  attn2<<<dim3(16, 16, 2), 256, 0, stream>>>(qb, kb, vtb, yb);

  gemm11<128, 1><<<dim3(16, 16), 512, 0, stream>>>(yb, cpb, cp_b, (float*)d_out,
                                                   nullptr, nullptr, 1.0f);
}

// Round 15
// 171.919 us; speedup vs baseline: 1.0590x; 1.0140x over previous
//
#include <hip/hip_runtime.h>

typedef unsigned short u16;
typedef __bf16 bf16x8 __attribute__((ext_vector_type(8)));
typedef float f32x4 __attribute__((ext_vector_type(4)));
typedef float f32x16 __attribute__((ext_vector_type(16)));
typedef unsigned u32x4 __attribute__((ext_vector_type(4)));

#define T_   2048
#define C_   2048
#define HD_  128
#define NH_  16
#define NKV_ 4
#define M_   4096   // B*T

typedef __attribute__((address_space(1))) const void* as1_cvp;
typedef __attribute__((address_space(3))) void* as3_vp;

__device__ __forceinline__ void gload16(const void* g, void* l) {
  __builtin_amdgcn_global_load_lds((as1_cvp)g, (as3_vp)l, 16, 0, 0);
}

__device__ __forceinline__ u16 f2bf(float f) {
  unsigned u = __builtin_bit_cast(unsigned, f);
  return (u16)((u + 0x7fffu + ((u >> 16) & 1u)) >> 16);
}

__device__ __forceinline__ float fexp2(float x) {
  float r;
  asm("v_exp_f32 %0, %1" : "=v"(r) : "v"(x));
  return r;
}

__device__ __forceinline__ unsigned cvtpk(float a, float b) {
  unsigned d;
  asm("v_cvt_pk_bf16_f32 %0, %1, %2" : "=v"(d) : "v"(a), "v"(b));
  return d;
}

// ---------------- fused prep: all fp32->bf16 conversions + RoPE folds + biases, ONE launch ----
__device__ __forceinline__ void cvt4(const float* __restrict__ src, u16* __restrict__ dst, int i) {
  float4 v = ((const float4*)src)[i];
  ushort4 r;
  r.x = f2bf(v.x); r.y = f2bf(v.y); r.z = f2bf(v.z); r.w = f2bf(v.w);
  ((ushort4*)dst)[i] = r;
}

// RoPE fold on weight-row pairs (angle indexed by HEAD, per reference quirk)
__device__ __forceinline__ void rope_item(const float* __restrict__ W, u16* __restrict__ out, int i) {
  const int p  = i >> 9;            // row-pair index
  const int c4 = (i & 511) << 2;    // float column
  const int h  = p >> 6;
  const int ii = p & 63;
  const float theta = __expf(-(float)ii * (9.210340371976184f / 64.0f));
  float s, c;
  __sincosf((float)h * theta, &s, &c);
  const size_t r0 = (size_t)(2 * p) * 2048 + c4;
  const size_t r1 = r0 + 2048;
  float4 a = *(const float4*)(W + r0);
  float4 b = *(const float4*)(W + r1);
  ushort4 o0, o1;
  o0.x = f2bf(a.x * c - b.x * s); o0.y = f2bf(a.y * c - b.y * s);
  o0.z = f2bf(a.z * c - b.z * s); o0.w = f2bf(a.w * c - b.w * s);
  o1.x = f2bf(b.x * c + a.x * s); o1.y = f2bf(b.y * c + a.y * s);
  o1.z = f2bf(b.z * c + a.z * s); o1.w = f2bf(b.w * c + a.w * s);
  *(ushort4*)(out + r0) = o0;
  *(ushort4*)(out + r1) = o1;
}

__global__ void prep_all(const float* __restrict__ x,    const float* __restrict__ wq_w,
                         const float* __restrict__ wk_w, const float* __restrict__ wv_w,
                         const float* __restrict__ cp_w, const float* __restrict__ wq_b,
                         const float* __restrict__ wk_b, const float* __restrict__ wv_b,
                         u16* __restrict__ xb,  u16* __restrict__ wqr, u16* __restrict__ wkr,
                         u16* __restrict__ wvb, u16* __restrict__ cpb, float* __restrict__ bqkv) {
  int i = blockIdx.x * blockDim.x + threadIdx.x;
  if (i < 2097152) { cvt4(x, xb, i); return; }            // x  [4096x2048]
  i -= 2097152;
  if (i < 262144)  { cvt4(wv_w, wvb, i); return; }        // wv [512x2048]
  i -= 262144;
  if (i < 1048576) { cvt4(cp_w, cpb, i); return; }        // cp [2048x2048]
  i -= 1048576;
  if (i < 524288)  { rope_item(wq_w, wqr, i); return; }   // wq rope (1024 pairs x 512)
  i -= 524288;
  if (i < 131072)  { rope_item(wk_w, wkr, i); return; }   // wk rope (256 pairs x 512)
  i -= 131072;
  if (i < 1280) {                                          // rope'd biases
    const float* src = (i < 1024) ? wq_b : wk_b;
    float* dst = (i < 1024) ? bqkv : (bqkv + 2048);
    const int p = (i < 1024) ? i : (i - 1024);
    const int ii = p & 63;
    const float theta = __expf(-(float)ii * (9.210340371976184f / 64.0f));
    float s, c;
    __sincosf((float)(p >> 6) * theta, &s, &c);
    const float a = src[2 * p], b = src[2 * p + 1];
    dst[2 * p]     = a * c - b * s;
    dst[2 * p + 1] = b * c + a * s;
  } else if (i < 1536) {
    const int p = i - 1280;
    bqkv[2560 + 2 * p]     = wv_b[2 * p];
    bqkv[2560 + 2 * p + 1] = wv_b[2 * p + 1];
  }
}

// ---------------- compiler-interleaved GEMM (best-known) + T1 XCD grid swizzle ------------
// BM=256, K-step 64, 8 waves as 4M x 2N (wave tile 64 x BN/2). A TRIPLE-buffered (staged
// 2 K-steps ahead), B double-buffered (1 ahead); issue order B(s+1) then A(s+2) makes the
// once-per-K-step s_waitcnt vmcnt(4) retire exactly {A(s+1),B(s+1)} while A(s+2) stays in
// flight. ONE s_barrier per K-step; body UNPINNED so the compiler interleaves MFMA with
// counted lgkmcnt and drifting waves overlap the LDS and MFMA pipes.
// T1: 1-D grid of 256 blocks, bijective XCD remap (xcd = bid&7 under round-robin dispatch):
// each XCD owns 2 contiguous M-panels (A footprint 2 MB -> L2-resident) x all 16 N-cols.
// Swizzle: phys 16B-slot = logical ^ (row&7) via inverse-swizzled global source (rule 21;
// measured 0 bank conflicts). MODE 0: fused QKV epilogue (BN=192); MODE 1: fp32 out (BN=128).
template<int BN, int MODE>
__global__ __launch_bounds__(512)
void gemm11(const u16* __restrict__ A, const u16* __restrict__ W,
            const float* __restrict__ bias, void* __restrict__ op0,
            void* __restrict__ op1, void* __restrict__ op2, const float qscale) {
  constexpr int NREP = BN / 32;
  constexpr int ABUF = 16384;
  constexpr int BBUF = BN * 64;
  constexpr int NBL  = BN / 64;
  __shared__ __align__(16) u16 sm[3 * ABUF + 2 * BBUF];
  const int tid  = threadIdx.x;
  const int lane = tid & 63;
  const int wid  = tid >> 6;
  const int wr = wid >> 1, wc = wid & 1;
  // T1 bijective XCD remap: bid 0..255 -> (m-panel, n-col); xcd owns m-panels {2x, 2x+1}
  const int bid = blockIdx.x;
  const int xcd = bid & 7;
  const int lix = bid >> 3;                 // 0..31
  const int m0 = ((xcd << 1) + (lix >> 4)) << 8;
  const int n0 = (lix & 15) * BN;
  const int K  = C_;
  const int fr = lane & 15, g = lane >> 4;
  const int rs0 = ((g ^ (fr & 7)) << 3);
  const int rs1 = (((4 + g) ^ (fr & 7)) << 3);

  size_t sofA[4]; int sdstA[4];
#pragma unroll
  for (int l = 0; l < 4; ++l) {
    const int j = l * 512 + tid, rl = j >> 3, sl = j & 7;
    sofA[l] = (size_t)rl * K + ((sl ^ (rl & 7)) << 3);
    sdstA[l] = j * 8;
  }
  size_t sofB[NBL]; int sdstB[NBL];
#pragma unroll
  for (int l = 0; l < NBL; ++l) {
    const int j = l * 512 + tid, rl = j >> 3, sl = j & 7;
    sofB[l] = (size_t)rl * K + ((sl ^ (rl & 7)) << 3);
    sdstB[l] = j * 8;
  }
  const u16* Ab = A + (size_t)m0 * K;
  const u16* Bb = W + (size_t)n0 * K;

  f32x4 acc[4][NREP] = {};

#define SA(l, ks, buf) gload16(Ab + (size_t)(ks) * 64 + sofA[l], sm + (buf) * ABUF + sdstA[l]);
#define SB(l, ks, buf) gload16(Bb + (size_t)(ks) * 64 + sofB[l], sm + 3 * ABUF + (buf) * BBUF + sdstB[l]);

  // prologue: B(0), A(0), A(1); vmcnt(4) leaves A(1) in flight
#pragma unroll
  for (int l = 0; l < NBL; ++l) SB(l, 0, 0)
#pragma unroll
  for (int l = 0; l < 4; ++l) SA(l, 0, 0)
#pragma unroll
  for (int l = 0; l < 4; ++l) SA(l, 1, 1)
  asm volatile("s_waitcnt vmcnt(4)" ::: "memory");
  __builtin_amdgcn_s_barrier();
  __builtin_amdgcn_sched_barrier(0);

  int a0 = 0, a2 = 2;
  for (int s = 0; s < 32; ++s) {
    const int ab = a0 * ABUF;
    const int bb = 3 * ABUF + (s & 1) * BBUF;
    const int b1 = (s & 1) ^ 1;
    bf16x8 af0[4], af1[4], bq0[NREP], bq1[NREP];
#pragma unroll
    for (int ni = 0; ni < NREP; ++ni)
      bq0[ni] = *(const bf16x8*)&sm[bb + (wc * (BN / 2) + ni * 16 + fr) * 64 + rs0];
#pragma unroll
    for (int mi = 0; mi < 4; ++mi)
      af0[mi] = *(const bf16x8*)&sm[ab + (wr * 64 + mi * 16 + fr) * 64 + rs0];
#pragma unroll
    for (int ni = 0; ni < NREP; ++ni)
      bq1[ni] = *(const bf16x8*)&sm[bb + (wc * (BN / 2) + ni * 16 + fr) * 64 + rs1];
#pragma unroll
    for (int mi = 0; mi < 4; ++mi)
      af1[mi] = *(const bf16x8*)&sm[ab + (wr * 64 + mi * 16 + fr) * 64 + rs1];
    if (s < 31) {
#pragma unroll
      for (int l = 0; l < NBL; ++l) SB(l, s + 1, b1)
    }
    if (s < 30) {
#pragma unroll
      for (int l = 0; l < 4; ++l) SA(l, s + 2, a2)
    }
    __builtin_amdgcn_s_setprio(1);
#pragma unroll
    for (int mi = 0; mi < 4; ++mi)
#pragma unroll
      for (int ni = 0; ni < NREP; ++ni)
        acc[mi][ni] = __builtin_amdgcn_mfma_f32_16x16x32_bf16(af0[mi], bq0[ni], acc[mi][ni], 0, 0, 0);
#pragma unroll
    for (int mi = 0; mi < 4; ++mi)
#pragma unroll
      for (int ni = 0; ni < NREP; ++ni)
        acc[mi][ni] = __builtin_amdgcn_mfma_f32_16x16x32_bf16(af1[mi], bq1[ni], acc[mi][ni], 0, 0, 0);
    __builtin_amdgcn_s_setprio(0);
    if (s < 30)       asm volatile("s_waitcnt vmcnt(4)" ::: "memory");
    else if (s == 30) asm volatile("s_waitcnt vmcnt(0)" ::: "memory");
    if (s < 31) {
      __builtin_amdgcn_s_barrier();
      __builtin_amdgcn_sched_barrier(0);
    }
    a0 = (a0 == 2) ? 0 : a0 + 1;
    a2 = (a2 == 2) ? 0 : a2 + 1;
  }
#undef SA
#undef SB

#pragma unroll
  for (int mi = 0; mi < 4; ++mi) {
    const int rg0 = m0 + wr * 64 + mi * 16 + ((lane >> 4) << 2);
#pragma unroll
    for (int ni = 0; ni < NREP; ++ni) {
      const int cg = n0 + wc * (BN / 2) + ni * 16 + fr;
      const float bb2 = bias[cg];
#pragma unroll
      for (int r = 0; r < 4; ++r) {
        float v = acc[mi][ni][r] + bb2;
        const int rg = rg0 + r;
        if (MODE == 1) {
          ((float*)op0)[(size_t)rg * C_ + cg] = v;
        } else {
          const int b = rg >> 11, t = rg & (T_ - 1);
          if (cg < 2048) {
            const int h = cg >> 7, d = cg & 127;
            ((u16*)op0)[((((size_t)b * NH_ + h) * T_ + t) << 7) + d] = f2bf(v * qscale);
          } else if (cg < 2560) {
            const int c2 = cg - 2048, h = c2 >> 7, d = c2 & 127;
            ((u16*)op1)[((((size_t)b * NKV_ + h) * T_ + t) << 7) + d] = f2bf(v);
          } else {
            const int c2 = cg - 2560, h = c2 >> 7, d = c2 & 127;
            ((u16*)op2)[(((size_t)b * NKV_ + h) * HD_ + d) * T_ + t] = f2bf(v);
          }
        }
      }
    }
  }
}

// ---------------- causal GQA flash attention (best-known) ------------
__device__ __forceinline__ void stage_kv(u16* dst, const u16* __restrict__ kg,
                                         const u16* __restrict__ vg, int lane, int w) {
#pragma unroll
  for (int r = 0; r < 4; ++r) {
    const int row = r * 16 + w * 4 + (lane >> 4);
    const int cg  = (lane & 15) ^ (row & 7);
    gload16(kg + (size_t)row * 128 + cg * 8, dst + row * 128 + (lane & 15) * 8);
  }
#pragma unroll
  for (int r = 0; r < 4; ++r) {
    const int row = r * 32 + w * 8 + (lane >> 3);
    const int cg  = (lane & 7) ^ (row & 7);
    gload16(vg + (size_t)row * T_ + cg * 8, dst + 8192 + row * 64 + (lane & 7) * 8);
  }
}

__global__ __launch_bounds__(256, 2)
void attn2(const u16* __restrict__ q, const u16* __restrict__ k,
           const u16* __restrict__ vt, u16* __restrict__ y) {
  __shared__ __align__(16) u16 sm[32768];
  const int tid  = threadIdx.x;
  const int lane = tid & 63;
  const int w    = tid >> 6;
  const int hi   = lane >> 5;
  const int l5   = lane & 31;
  const int h = blockIdx.y;
  const int b = blockIdx.z;
  // complementary pairing: co-resident (x,y,0)/(x,y,1) get qt summing to 15 -> uniform CU load
  const int qt = b ? (int)blockIdx.x : (15 - (int)blockIdx.x);
  const int q0  = qt << 7;
  const int q0w = q0 + w * 32;
  const int nkv = 2 * qt + 2;
  const size_t qbase = (((size_t)b * NH_ + h) * T_ + q0) * HD_;
  const size_t kbase = ((size_t)b * NKV_ + (h >> 2)) * (size_t)T_ * HD_;
  const size_t vbase = ((size_t)b * NKV_ + (h >> 2)) * (size_t)HD_ * T_;

#pragma unroll
  for (int r = 0; r < 8; ++r) {
    const int row = r * 16 + w * 4 + (lane >> 4);
    const int cg  = (lane & 15) ^ (row & 7);
    gload16(q + qbase + (size_t)row * 128 + cg * 8, sm + row * 128 + (lane & 15) * 8);
  }
  __syncthreads();
  bf16x8 qf[8];
  {
    const int row = w * 32 + l5;
#pragma unroll
    for (int kd = 0; kd < 8; ++kd)
      qf[kd] = *(const bf16x8*)&sm[row * 128 + ((((kd << 1) | hi) ^ (row & 7)) << 3)];
  }
  __syncthreads();
  stage_kv(sm, k + kbase, vt + vbase, lane, w);

  f32x16 o[4] = {};
  float m = -1e30f, l = 0.f;

  for (int kv = 0; kv < nkv; ++kv) {
    __syncthreads();
    const int buf = kv & 1;
    if (kv + 1 < nkv)
      stage_kv(sm + ((buf ^ 1) << 14),
               k + kbase + ((size_t)(kv + 1) << 6) * 128,
               vt + vbase + ((kv + 1) << 6), lane, w);

    if ((kv << 6) <= q0w + 31) {
      const u16* Ks = sm + (buf << 14);
      const u16* Vs = Ks + 8192;

      f32x16 st[2] = {};
      __builtin_amdgcn_s_setprio(1);
#pragma unroll
      for (int kt = 0; kt < 2; ++kt) {
        const int krow = kt * 32 + l5;
#pragma unroll
        for (int kd = 0; kd < 8; ++kd) {
          bf16x8 ka = *(const bf16x8*)&Ks[krow * 128 + ((((kd << 1) | hi) ^ (l5 & 7)) << 3)];
          st[kt] = __builtin_amdgcn_mfma_f32_32x32x16_bf16(ka, qf[kd], st[kt], 0, 0, 0);
        }
      }
      __builtin_amdgcn_s_setprio(0);

      if ((kv << 6) + 63 > q0w) {
        const int qg = q0w + l5;
#pragma unroll
        for (int kt = 0; kt < 2; ++kt)
#pragma unroll
          for (int r = 0; r < 16; ++r) {
            const int kg = (kv << 6) + kt * 32 + (r & 3) + ((r >> 2) << 3) + (hi << 2);
            if (kg > qg) st[kt][r] = -3.0e38f;
          }
      }

      float pmax = -3.0e38f;
#pragma unroll
      for (int kt = 0; kt < 2; ++kt)
#pragma unroll
        for (int r = 0; r < 16; ++r) pmax = fmaxf(pmax, st[kt][r]);
      pmax = fmaxf(pmax, __shfl_xor(pmax, 32));
      if (!__all(pmax - m <= 8.0f)) {
        const float mn = fmaxf(m, pmax);
        const float f = fexp2(m - mn);
        m = mn;
        l *= f;
#pragma unroll
        for (int r = 0; r < 16; ++r) {
          const float fr = __shfl(f, (r & 3) + ((r >> 2) << 3) + (hi << 2));
          o[0][r] *= fr; o[1][r] *= fr; o[2][r] *= fr; o[3][r] *= fr;
        }
      }

      float rs = 0.f;
#pragma unroll
      for (int kt = 0; kt < 2; ++kt) {
#pragma unroll
        for (int s = 0; s < 2; ++s) {
          float e0 = fexp2(st[kt][8 * s + 0] - m), e1 = fexp2(st[kt][8 * s + 1] - m);
          float e2 = fexp2(st[kt][8 * s + 2] - m), e3 = fexp2(st[kt][8 * s + 3] - m);
          float e4 = fexp2(st[kt][8 * s + 4] - m), e5 = fexp2(st[kt][8 * s + 5] - m);
          float e6 = fexp2(st[kt][8 * s + 6] - m), e7 = fexp2(st[kt][8 * s + 7] - m);
          rs += ((e0 + e1) + (e2 + e3)) + ((e4 + e5) + (e6 + e7));
          const unsigned wL0 = cvtpk(e0, e1), wL1 = cvtpk(e2, e3);
          const unsigned wH0 = cvtpk(e4, e5), wH1 = cvtpk(e6, e7);
          const unsigned s0 = hi ? wL0 : wH0, s1 = hi ? wL1 : wH1;
          const unsigned r0 = __shfl_xor(s0, 32), r1 = __shfl_xor(s1, 32);
          u32x4 fw;
          fw.x = hi ? r0 : wL0; fw.y = hi ? r1 : wL1;
          fw.z = hi ? wH0 : r0; fw.w = hi ? wH1 : r1;
          const bf16x8 pa = __builtin_bit_cast(bf16x8, fw);
          const int ch = (((kt * 2 + s) << 1) | hi) ^ (l5 & 7);
          __builtin_amdgcn_s_setprio(1);
#pragma unroll
          for (int ds = 0; ds < 4; ++ds) {
            const int vrow = ds * 32 + l5;
            bf16x8 vb = *(const bf16x8*)&Vs[vrow * 64 + (ch << 3)];
            o[ds] = __builtin_amdgcn_mfma_f32_32x32x16_bf16(pa, vb, o[ds], 0, 0, 0);
          }
          __builtin_amdgcn_s_setprio(0);
        }
      }
      rs += __shfl_xor(rs, 32);
      l += rs;
    }
  }

  const float linv = 1.0f / l;
#pragma unroll
  for (int r = 0; r < 16; ++r) {
    const int crow = (r & 3) + ((r >> 2) << 3) + (hi << 2);
    const float lf = __shfl(linv, crow);
    const int qg = q0w + crow;
    const size_t rowoff = (((size_t)(b << 11) + qg) << 11) + (h << 7) + l5;
#pragma unroll
    for (int ds = 0; ds < 4; ++ds)
      y[rowoff + ds * 32] = f2bf(o[ds][r] * lf);
  }
}

// ---------------- launch ----------------
extern "C" void kernel_launch(void* const* d_in, const int* in_sizes, int n_in,
                              void* d_out, int out_size, void* d_ws, size_t ws_size,
                              hipStream_t stream) {
  (void)in_sizes; (void)n_in; (void)out_size; (void)ws_size;
  const float* x    = (const float*)d_in[0];
  const float* wq_w = (const float*)d_in[1];
  const float* wq_b = (const float*)d_in[2];
  const float* wk_w = (const float*)d_in[3];
  const float* wk_b = (const float*)d_in[4];
  const float* wv_w = (const float*)d_in[5];
  const float* wv_b = (const float*)d_in[6];
  const float* cp_w = (const float*)d_in[7];
  const float* cp_b = (const float*)d_in[8];

  char* ws = (char*)d_ws;
  u16* xb  = (u16*)ws;  ws += (size_t)M_ * C_ * 2;        // x bf16; later reused as y
  u16* wqr = (u16*)ws;  ws += (size_t)C_ * C_ * 2;        // rotated wq
  u16* wkr = (u16*)ws;  ws += (size_t)512 * C_ * 2;       // rotated wk
  u16* wvb = (u16*)ws;  ws += (size_t)512 * C_ * 2;       // wv bf16
  u16* cpb = (u16*)ws;  ws += (size_t)C_ * C_ * 2;
  u16* qb  = (u16*)ws;  ws += (size_t)M_ * C_ * 2;
  u16* kb  = (u16*)ws;  ws += (size_t)M_ * 512 * 2;
  u16* vtb = (u16*)ws;  ws += (size_t)M_ * 512 * 2;
  float* bqkv = (float*)ws; ws += 3072 * 4;               // concat bias (fp32)
  u16* yb = xb;

  // single fused prep launch: 4,064,768 items = 15878 blocks x 256
  prep_all<<<15878, 256, 0, stream>>>(x, wq_w, wk_w, wv_w, cp_w, wq_b, wk_b, wv_b,
                                      xb, wqr, wkr, wvb, cpb, bqkv);

  // Q pre-scaled by log2e / sqrt(HD) so attention softmax runs in exp2 domain
  const float qscale = 0.08838834764831843f * 1.4426950408889634f;
  gemm11<192, 0><<<256, 512, 0, stream>>>(xb, wqr, bqkv, qb, kb, vtb, qscale);

  attn2<<<dim3(16, 16, 2), 256, 0, stream>>>(qb, kb, vtb, yb);

  gemm11<128, 1><<<256, 512, 0, stream>>>(yb, cpb, cp_b, (float*)d_out,
                                          nullptr, nullptr, 1.0f);
}